// Round 18
// baseline (224.904 us; speedup 1.0000x reference)
//
#include <hip/hip_runtime.h>
#include <hip/hip_bf16.h>
#include <stdint.h>

typedef unsigned short u16;
typedef __attribute__((ext_vector_type(8))) short bf16x8;
typedef __attribute__((ext_vector_type(4))) short bf16x4;
typedef __attribute__((ext_vector_type(4))) float f32x4;
typedef __attribute__((ext_vector_type(16))) float f32x16;
typedef __attribute__((ext_vector_type(4))) unsigned short u16x4;

#define DEVI static __device__ __forceinline__

DEVI u16 f2bf(float f) {
    unsigned int u = __builtin_bit_cast(unsigned int, f);
    return (u16)((u + 0x7fffu + ((u >> 16) & 1u)) >> 16);
}

DEVI float bf2f(u16 v) { return __builtin_bit_cast(float, ((unsigned)v) << 16); }

DEVI float4 ldbf4(const u16* p, size_t idx4) {
    const u16x4 v = ((const u16x4*)p)[idx4];
    float4 o;
    o.x = bf2f(v[0]); o.y = bf2f(v[1]); o.z = bf2f(v[2]); o.w = bf2f(v[3]);
    return o;
}

DEVI float gelu_f(float v) {
    // tanh-form GELU: x * sigmoid(1.5957691(x + 0.044715 x^3)); |err vs exact| <= ~3e-4
    const float z = 1.5957691216f * (v + 0.044715f * v * v * v);
    return v / (1.0f + __expf(-z));
}

DEVI void async_copy16(const void* g, void* l) {
    __builtin_amdgcn_global_load_lds((const __attribute__((address_space(1))) void*)g,
                                     (__attribute__((address_space(3))) void*)l,
                                     16, 0, 0);
}

// ============ prep kernel: 4x weight transpose-convert + LN1, one launch ============
__global__ __launch_bounds__(256) void prep_kernel(const float* __restrict__ wq, u16* __restrict__ dq,
                                                   const float* __restrict__ wp, u16* __restrict__ dp,
                                                   const float* __restrict__ w1, u16* __restrict__ d1,
                                                   const float* __restrict__ w2, u16* __restrict__ d2,
                                                   const float* __restrict__ x,
                                                   const float* __restrict__ g1,
                                                   const float* __restrict__ be1,
                                                   u16* __restrict__ ln1out) {
    __shared__ float tile[32][33];
    __shared__ float red[8];
    const int id = blockIdx.x;
    const int t = threadIdx.x;
    if (id >= 12288) {
        const int row = id - 12288;
        const float4 v = ((const float4*)(x + (size_t)row * 1024))[t];
        float s  = v.x + v.y + v.z + v.w;
        float ss = v.x * v.x + v.y * v.y + v.z * v.z + v.w * v.w;
#pragma unroll
        for (int off = 32; off > 0; off >>= 1) {
            s  += __shfl_down(s, off);
            ss += __shfl_down(ss, off);
        }
        const int wv = t >> 6;
        if ((t & 63) == 0) { red[wv] = s; red[4 + wv] = ss; }
        __syncthreads();
        if (t == 0) {
            red[0] = red[0] + red[1] + red[2] + red[3];
            red[4] = red[4] + red[5] + red[6] + red[7];
        }
        __syncthreads();
        const float mean = red[0] * (1.0f / 1024.0f);
        const float var  = red[4] * (1.0f / 1024.0f) - mean * mean;
        const float rstd = rsqrtf(var + 1e-5f);
        const float4 gv = ((const float4*)g1)[t];
        const float4 bv = ((const float4*)be1)[t];
        u16x4 o;
        o[0] = f2bf((v.x - mean) * rstd * gv.x + bv.x);
        o[1] = f2bf((v.y - mean) * rstd * gv.y + bv.y);
        o[2] = f2bf((v.z - mean) * rstd * gv.z + bv.z);
        o[3] = f2bf((v.w - mean) * rstd * gv.w + bv.w);
        ((u16x4*)ln1out)[(size_t)row * 256 + t] = o;
        return;
    }
    const float* src; u16* dst; int K, N, k0, n0;
    if (id < 3072)      {               src = wq; dst = dq; K = 1024; N = 3072; k0 = (id & 31) << 5; n0 = (id >> 5) << 5; }
    else if (id < 4096) { int l = id - 3072; src = wp; dst = dp; K = 1024; N = 1024; k0 = (l & 31) << 5; n0 = (l >> 5) << 5; }
    else if (id < 8192) { int l = id - 4096; src = w1; dst = d1; K = 1024; N = 4096; k0 = (l & 31) << 5; n0 = (l >> 5) << 5; }
    else                { int l = id - 8192; src = w2; dst = d2; K = 4096; N = 1024; k0 = (l & 127) << 5; n0 = (l >> 7) << 5; }
    const int c = t & 31, r0 = t >> 5;
#pragma unroll
    for (int p = 0; p < 4; ++p) {
        const int r = r0 + p * 8;
        tile[r][c] = src[(size_t)(k0 + r) * N + n0 + c];
    }
    __syncthreads();
#pragma unroll
    for (int p = 0; p < 4; ++p) {
        const int r = r0 + p * 8;
        dst[(size_t)(n0 + r) * K + k0 + c] = f2bf(tile[c][r]);
    }
}

// ================= 128x128 GEMM, BK=64, single-buffer, m97-pure schedule =================
DEVI void stage64(const char* g, size_t ldb, char* lds0, int lane, int wv) {
    const int colsw = ((lane & 3) << 4) ^ (lane & 32);
    const int rl = lane >> 2;
#pragma unroll
    for (int i = 0; i < 4; ++i) {
        const int s = wv * 4 + i;
        const int kh = s >> 3, c = s & 7;
        async_copy16(g + (size_t)(c * 16 + rl) * ldb + kh * 64 + colsw,
                     lds0 + s * 1024);
    }
}

// EPI 0: QKV scatter. EPI 5: bf16 partial (split-K).
template <int EPI, int SPLITK>
__global__ __launch_bounds__(256, 4) void gemmv6(const u16* __restrict__ A,
                                                 const u16* __restrict__ Bt,
                                                 const float* __restrict__ bias,
                                                 void* __restrict__ out0,
                                                 void* __restrict__ out1,
                                                 void* __restrict__ out2,
                                                 int M, int N, int K) {
    __shared__ __align__(16) char As[16384];
    __shared__ __align__(16) char Bs[16384];
    const int tid = threadIdx.x;
    const int lane = tid & 63, wv = tid >> 6;
    const int wr = wv >> 1, wc = wv & 1;
    const int g = lane >> 4, qq = lane & 15;
    const int rdoff = qq * 64 + ((g * 16) ^ ((qq & 8) << 2));

    const int nwg = gridDim.x;
    int id = blockIdx.x;
    id = (id & 7) * (nwg >> 3) + (id >> 3);
    const int MT = M >> 7, NTn = N >> 7;
    const int slice = id / (MT * NTn);
    const int r2 = id % (MT * NTn);
    const int m0 = (r2 % MT) << 7;
    const int n0 = (r2 / MT) << 7;
    const int Ks = K / SPLITK;
    const int NT = Ks >> 6;
    const size_t ldb = (size_t)K * 2;

    const char* pa = (const char*)A + (size_t)m0 * ldb + (size_t)slice * Ks * 2;
    const char* pb = (const char*)Bt + (size_t)n0 * ldb + (size_t)slice * Ks * 2;

    f32x4 acc[4][4] = {};

    for (int t = 0; t < NT; ++t) {
        stage64(pa + (size_t)t * 128, ldb, As, lane, wv);
        stage64(pb + (size_t)t * 128, ldb, Bs, lane, wv);
        __syncthreads();
#pragma unroll
        for (int kh = 0; kh < 2; ++kh) {
            bf16x8 fa[4], fb[4];
#pragma unroll
            for (int fn = 0; fn < 4; ++fn)
                fb[fn] = *(const bf16x8*)(Bs + (kh * 8 + wc * 4 + fn) * 1024 + rdoff);
#pragma unroll
            for (int fm = 0; fm < 4; ++fm)
                fa[fm] = *(const bf16x8*)(As + (kh * 8 + wr * 4 + fm) * 1024 + rdoff);
#pragma unroll
            for (int fm = 0; fm < 4; ++fm)
#pragma unroll
                for (int fn = 0; fn < 4; ++fn)
                    acc[fm][fn] = __builtin_amdgcn_mfma_f32_16x16x32_bf16(fa[fm], fb[fn],
                                                                          acc[fm][fn], 0, 0, 0);
        }
        __syncthreads();
    }

#pragma unroll
    for (int fm = 0; fm < 4; ++fm) {
#pragma unroll
        for (int fn = 0; fn < 4; ++fn) {
            const int mrow = m0 + wr * 64 + fm * 16 + g * 4;
            const int ncol = n0 + wc * 64 + fn * 16 + qq;
            if constexpr (EPI == 0) {
                const float bs = bias[ncol];
                const int sec = ncol >> 10;
                const int hd_ = ncol & 1023;
                const int hh = hd_ >> 6, dd = hd_ & 63;
                if (sec == 2) {
                    const int b_ = mrow >> 11, l_ = mrow & 2047;
                    u16x4 pk;
#pragma unroll
                    for (int r = 0; r < 4; ++r) pk[r] = f2bf(acc[fm][fn][r] + bs);
                    *(u16x4*)((u16*)out2 + ((size_t)((b_ * 16 + hh) * 64 + dd)) * 2048 + l_) = pk;
                } else {
                    u16* dst = (sec == 0) ? (u16*)out0 : (u16*)out1;
                    const float sc = (sec == 0) ? 0.1803368801f : 1.0f;
#pragma unroll
                    for (int r = 0; r < 4; ++r) {
                        const int mr = mrow + r;
                        const int b_ = mr >> 11, l_ = mr & 2047;
                        dst[((size_t)((b_ * 16 + hh) * 2048 + l_)) * 64 + dd] =
                            f2bf((acc[fm][fn][r] + bs) * sc);
                    }
                }
            } else {  // EPI 5: bf16 partial for split-K
                u16* dst = (u16*)out0 + (size_t)slice * M * N;
#pragma unroll
                for (int r = 0; r < 4; ++r)
                    dst[(size_t)(mrow + r) * N + ncol] = f2bf(acc[fm][fn][r]);
            }
        }
    }
}

// ================= 256x256 8-phase GEMM: 8 DISTINCT LDS arrays, counted vmcnt =================
// 512 thr (8 waves 2Mx4N, per-wave 128x64), BK=64, K multiple of 128. LDS = 8 x 16KB.
// Arrays A{buf}{kh}/B{buf}{kh} have COMPILE-TIME identity (fully unrolled 2-tile iteration)
// so alias analysis cannot force vmcnt drains (R3 failure mechanism). Ledger (per-lane, 2
// loads/stage): stages P1:A11<-(t+1)k1, P2:B11, P3:A00<-(t+2)k0, P4:B00 +vmcnt(4),
// P5:A01<-(t+2)k1, P6:B01, P7:A10<-(t+3)k0, P8:B10 +vmcnt(4). Every read's source stage is
// >= 3 stages older than the nearest vmcnt(4) guarantee (verified slot-by-slot). Tail: dead
// clamped stages keep vmcnt counts uniform. ds_read/MFMA/epilogue addressing = R3 (passed).
DEVI void stage_half8(const char* g, size_t ldb, char* lds0, int lane, int wv) {
    const int colsw = ((lane & 3) << 4) ^ (lane & 32);
    const int rl = lane >> 2;
#pragma unroll
    for (int i = 0; i < 2; ++i) {
        const int c = wv + i * 8;   // subtile 0..15 (16 rows x 32 cols each)
        async_copy16(g + (size_t)(c * 16 + rl) * ldb + colsw, lds0 + c * 1024);
    }
}

template <int EPI, int SPLITK>
__global__ __launch_bounds__(512, 1) void gemm8(const u16* __restrict__ A,
                                                const u16* __restrict__ Bt,
                                                const float* __restrict__ bias,
                                                void* __restrict__ out0,
                                                int M, int N, int K) {
    __shared__ __align__(16) char A00[16384];
    __shared__ __align__(16) char A01[16384];
    __shared__ __align__(16) char A10[16384];
    __shared__ __align__(16) char A11[16384];
    __shared__ __align__(16) char B00[16384];
    __shared__ __align__(16) char B01[16384];
    __shared__ __align__(16) char B10[16384];
    __shared__ __align__(16) char B11[16384];
    const int tid = threadIdx.x;
    const int lane = tid & 63, wv = tid >> 6;
    const int wr = wv >> 2, wc = wv & 3;        // 2M x 4N waves, 128x64 each
    const int g = lane >> 4, qq = lane & 15;
    const int rdoff = qq * 64 + ((g * 16) ^ ((qq & 8) << 2));

    int id = blockIdx.x;
    id = (id & 7) * (gridDim.x >> 3) + (id >> 3);
    const int MT = M >> 8, NTn = N >> 8;
    const int slice = id / (MT * NTn);
    const int r2 = id % (MT * NTn);
    const int m0 = (r2 % MT) << 8;
    const int n0 = (r2 / MT) << 8;
    const int Ks = K / SPLITK;
    const int NT = Ks >> 6;                      // even, >= 8 for our shapes
    const size_t ldb = (size_t)K * 2;

    const char* pa = (const char*)A + (size_t)m0 * ldb + (size_t)slice * Ks * 2;
    const char* pb = (const char*)Bt + (size_t)n0 * ldb + (size_t)slice * Ks * 2;

    f32x4 acc[8][4] = {};
    bf16x8 fb[4];

    auto dophase = [&](const char* Aks, const char* Bks, int MH,
                       const char* sg, char* sl) {
        if (MH == 0) {
#pragma unroll
            for (int fn = 0; fn < 4; ++fn)
                fb[fn] = *(const bf16x8*)(Bks + (wc * 4 + fn) * 1024 + rdoff);
        }
        bf16x8 fa[4];
#pragma unroll
        for (int i2 = 0; i2 < 4; ++i2)
            fa[i2] = *(const bf16x8*)(Aks + (wr * 8 + MH * 4 + i2) * 1024 + rdoff);
        stage_half8(sg, ldb, sl, lane, wv);
        __builtin_amdgcn_s_barrier();
        asm volatile("s_waitcnt lgkmcnt(0)" ::: "memory");
        __builtin_amdgcn_sched_barrier(0);
        __builtin_amdgcn_s_setprio(1);
#pragma unroll
        for (int fn = 0; fn < 4; ++fn)
#pragma unroll
            for (int i2 = 0; i2 < 4; ++i2)
                acc[MH * 4 + i2][fn] = __builtin_amdgcn_mfma_f32_16x16x32_bf16(
                    fa[i2], fb[fn], acc[MH * 4 + i2][fn], 0, 0, 0);
        __builtin_amdgcn_s_setprio(0);
        __builtin_amdgcn_sched_barrier(0);
    };

    // prologue: t0 kh0 (A00,B00), t0 kh1 (A01,B01), t1 kh0 (A10,B10); vmcnt(4) -> t0 landed
    stage_half8(pa,       ldb, A00, lane, wv);
    stage_half8(pb,       ldb, B00, lane, wv);
    stage_half8(pa + 64,  ldb, A01, lane, wv);
    stage_half8(pb + 64,  ldb, B01, lane, wv);
    stage_half8(pa + 128, ldb, A10, lane, wv);
    stage_half8(pb + 128, ldb, B10, lane, wv);
    asm volatile("s_waitcnt vmcnt(4)" ::: "memory");
    __builtin_amdgcn_s_barrier();

    const int NI = NT >> 1;
    for (int i = 0; i < NI; ++i) {
        const size_t t1o = (size_t)(2 * i + 1) * 128;
        const size_t t2o = (size_t)((2 * i + 2 < NT) ? 2 * i + 2 : NT - 1) * 128;
        const size_t t3o = (size_t)((2 * i + 3 < NT) ? 2 * i + 3 : NT - 1) * 128;

        // tile 2i (buf0)
        dophase(A00, B00, 0, pa + t1o + 64, A11);   // P1
        __builtin_amdgcn_s_barrier();
        dophase(A00, B00, 1, pb + t1o + 64, B11);   // P2
        __builtin_amdgcn_s_barrier();
        dophase(A01, B01, 0, pa + t2o,      A00);   // P3
        __builtin_amdgcn_s_barrier();
        dophase(A01, B01, 1, pb + t2o,      B00);   // P4
        asm volatile("s_waitcnt vmcnt(4)" ::: "memory");
        __builtin_amdgcn_s_barrier();
        // tile 2i+1 (buf1)
        dophase(A10, B10, 0, pa + t2o + 64, A01);   // P5
        __builtin_amdgcn_s_barrier();
        dophase(A10, B10, 1, pb + t2o + 64, B01);   // P6
        __builtin_amdgcn_s_barrier();
        dophase(A11, B11, 0, pa + t3o,      A10);   // P7
        __builtin_amdgcn_s_barrier();
        dophase(A11, B11, 1, pb + t3o,      B10);   // P8
        asm volatile("s_waitcnt vmcnt(4)" ::: "memory");
        __builtin_amdgcn_s_barrier();
    }

    // epilogue: lane holds D[g*4+r][qq] per 16x16 fragment (R3-verified)
#pragma unroll
    for (int fm = 0; fm < 8; ++fm) {
#pragma unroll
        for (int fn = 0; fn < 4; ++fn) {
            const int mrow = m0 + wr * 128 + fm * 16 + g * 4;
            const int ncol = n0 + wc * 64 + fn * 16 + qq;
            if constexpr (EPI == 2) {
                const float bs = bias[ncol];
                u16* dst = (u16*)out0;
#pragma unroll
                for (int r = 0; r < 4; ++r)
                    dst[(size_t)(mrow + r) * N + ncol] = f2bf(gelu_f(acc[fm][fn][r] + bs));
            } else {  // EPI 5: bf16 partial for split-K
                u16* dst = (u16*)out0 + (size_t)slice * M * N;
#pragma unroll
                for (int r = 0; r < 4; ++r)
                    dst[(size_t)(mrow + r) * N + ncol] = f2bf(acc[fm][fn][r]);
            }
        }
    }
}

// split-K reduce (bf16 partials) + bias + residual -> f32 out (FC2 path)
template <int SPLIT>
__global__ __launch_bounds__(256) void reduceN_kernel(const u16* __restrict__ p,
                                                      const float* __restrict__ bias,
                                                      const float* __restrict__ res,
                                                      float* __restrict__ out,
                                                      int MN4, int N4) {
    const int i = blockIdx.x * 256 + threadIdx.x;
    float4 s = ldbf4(p, i);
#pragma unroll
    for (int s2 = 1; s2 < SPLIT; ++s2) {
        const float4 q = ldbf4(p, (size_t)s2 * MN4 + i);
        s.x += q.x; s.y += q.y; s.z += q.z; s.w += q.w;
    }
    const float4 r = ((const float4*)res)[i];
    const float4 bs = ((const float4*)bias)[i & (N4 - 1)];
    float4 o;
    o.x = s.x + r.x + bs.x;
    o.y = s.y + r.y + bs.y;
    o.z = s.z + r.z + bs.z;
    o.w = s.w + r.w + bs.w;
    ((float4*)out)[i] = o;
}

// split-K reduce (bf16 partials) + bias + residual + LayerNorm fused (proj path)
template <int SPLIT>
__global__ __launch_bounds__(256) void reduceLN_kernel(const u16* __restrict__ p,
                                                       const float* __restrict__ bias,
                                                       const float* __restrict__ res,
                                                       const float* __restrict__ gw,
                                                       const float* __restrict__ bw,
                                                       float* __restrict__ xout,
                                                       u16* __restrict__ lnout,
                                                       int MN4) {
    const int row = blockIdx.x;
    const int t = threadIdx.x;
    const int i = row * 256 + t;
    float4 s = ldbf4(p, i);
#pragma unroll
    for (int s2 = 1; s2 < SPLIT; ++s2) {
        const float4 q = ldbf4(p, (size_t)s2 * MN4 + i);
        s.x += q.x; s.y += q.y; s.z += q.z; s.w += q.w;
    }
    const float4 r = ((const float4*)res)[i];
    const float4 bs = ((const float4*)bias)[t];
    float4 o;
    o.x = s.x + r.x + bs.x;
    o.y = s.y + r.y + bs.y;
    o.z = s.z + r.z + bs.z;
    o.w = s.w + r.w + bs.w;
    ((float4*)xout)[i] = o;
    float sum  = o.x + o.y + o.z + o.w;
    float ssum = o.x * o.x + o.y * o.y + o.z * o.z + o.w * o.w;
#pragma unroll
    for (int off = 32; off > 0; off >>= 1) {
        sum  += __shfl_down(sum, off);
        ssum += __shfl_down(ssum, off);
    }
    __shared__ float red[8];
    const int wv = t >> 6;
    if ((t & 63) == 0) { red[wv] = sum; red[4 + wv] = ssum; }
    __syncthreads();
    if (t == 0) {
        red[0] = red[0] + red[1] + red[2] + red[3];
        red[4] = red[4] + red[5] + red[6] + red[7];
    }
    __syncthreads();
    const float mean = red[0] * (1.0f / 1024.0f);
    const float var  = red[4] * (1.0f / 1024.0f) - mean * mean;
    const float rstd = rsqrtf(var + 1e-5f);
    const float4 gv = ((const float4*)gw)[t];
    const float4 bv = ((const float4*)bw)[t];
    u16x4 ov;
    ov[0] = f2bf((o.x - mean) * rstd * gv.x + bv.x);
    ov[1] = f2bf((o.y - mean) * rstd * gv.y + bv.y);
    ov[2] = f2bf((o.z - mean) * rstd * gv.z + bv.z);
    ov[3] = f2bf((o.w - mean) * rstd * gv.w + bv.w);
    ((u16x4*)lnout)[(size_t)row * 256 + t] = ov;
}

// ---------------- causal flash attention v7 (R17, plateau config) ----------------
DEVI void stage_kv1(const char* kbase, const char* vbase, int key0,
                    u16* ksm, u16* vsm, int wv, int lane) {
#pragma unroll
    for (int i = 0; i < 2; ++i) {
        const int c = wv + i * 4;
        const int off = c * 1024 + lane * 16;
        const int row = off >> 7;
        const int scol = (off & 127) ^ ((row & 7) << 4);
        async_copy16(kbase + (size_t)key0 * 128 + (size_t)row * 128 + scol,
                     (char*)ksm + c * 1024);
    }
#pragma unroll
    for (int i = 0; i < 2; ++i) {
        const int c = wv + i * 4;
        const int row = c * 8 + (lane >> 3);
        const int scol = ((lane & 7) * 16) ^ ((row & 7) << 4);
        async_copy16(vbase + (size_t)row * 4096 + (size_t)key0 * 2 + scol,
                     (char*)vsm + c * 1024);
    }
}

__global__ __launch_bounds__(256, 4) void attn32_seg(const u16* __restrict__ Q,
                                                     const u16* __restrict__ Kk,
                                                     const u16* __restrict__ Vt,
                                                     u16* __restrict__ opart,
                                                     float2* __restrict__ ml) {
    const int id = blockIdx.x;
    const int bh = id & 31;
    const int seg = (id >> 5) & 1;
    const int qb = 15 - (id >> 6);
    const int tid = threadIdx.x;
    const int wv = tid >> 6, lane = tid & 63;
    const int hi = lane >> 5, qc = lane & 31;

    __shared__ __align__(16) u16 Ksm[4096];
    __shared__ __align__(16) u16 Vsm[4096];
    __shared__ __align__(16) u16 Pl[4][32 * 36];

    const char* Kb = (const char*)(Kk + (size_t)bh * 2048 * 64);
    const char* Vb = (const char*)(Vt + (size_t)bh * 64 * 2048);
    u16* Pw = &Pl[wv][0];
    const u16* Pr = Pw + qc * 36;

    const int q0w = qb * 128 + wv * 32;
    const int qg = q0w + qc;
    const int nt_half = qb + 1;
    const int kt_begin = seg ? nt_half : 0;
    const int kt_end = seg ? (2 * qb + 2) : nt_half;
    const int ntw = min(kt_end, 2 * qb + (wv >> 1) + 1);

    bf16x8 qf[4];
    {
        const u16* Qp = Q + ((size_t)bh * 2048 + qg) * 64;
#pragma unroll
        for (int c = 0; c < 4; ++c)
            qf[c] = *(const bf16x8*)(Qp + c * 16 + hi * 8);
    }

    f32x16 oacc[2];
#pragma unroll
    for (int r = 0; r < 16; ++r) { oacc[0][r] = 0.0f; oacc[1][r] = 0.0f; }
    float m_run = -60000.0f, l_run = 0.0f;

    for (int kt = kt_begin; kt < kt_end; ++kt) {
        const int key0 = kt * 64;
        stage_kv1(Kb, Vb, key0, Ksm, Vsm, wv, lane);
        __syncthreads();
        if (kt < ntw) {
            f32x16 sacc[2];
#pragma unroll
            for (int r = 0; r < 16; ++r) { sacc[0][r] = 0.0f; sacc[1][r] = 0.0f; }
#pragma unroll
            for (int c = 0; c < 4; ++c) {
#pragma unroll
                for (int kb = 0; kb < 2; ++kb) {
                    const int kr = kb * 32 + qc;
                    const bf16x8 ak = *(const bf16x8*)((const char*)Ksm + kr * 128 +
                                          ((c * 32 + hi * 16) ^ ((kr & 7) << 4)));
                    sacc[kb] = __builtin_amdgcn_mfma_f32_32x32x16_bf16(ak, qf[c],
                                                                       sacc[kb], 0, 0, 0);
                }
            }
            float pmax = -1e30f;
            if (key0 + 63 > q0w) {
#pragma unroll
                for (int kb = 0; kb < 2; ++kb)
#pragma unroll
                    for (int r = 0; r < 16; ++r) {
                        const int key = key0 + kb * 32 + (r & 3) + 8 * (r >> 2) + 4 * hi;
                        float s = sacc[kb][r];
                        if (key > qg) s = -1e30f;
                        sacc[kb][r] = s;
                        pmax = fmaxf(pmax, s);
                    }
            } else {
#pragma unroll
                for (int kb = 0; kb < 2; ++kb)
#pragma unroll
                    for (int r = 0; r < 16; ++r) pmax = fmaxf(pmax, sacc[kb][r]);
            }
            pmax = fmaxf(pmax, __shfl_xor(pmax, 32));
            if (pmax > m_run + 11.0f) {
                const float alpha = __builtin_amdgcn_exp2f(m_run - pmax);
#pragma unroll
                for (int r = 0; r < 16; ++r) { oacc[0][r] *= alpha; oacc[1][r] *= alpha; }
                l_run *= alpha;
                m_run = pmax;
            }
            float lsum = 0.0f;
#pragma unroll
            for (int kb = 0; kb < 2; ++kb) {
#pragma unroll
                for (int j = 0; j < 4; ++j) {
                    u16x4 pk4;
#pragma unroll
                    for (int t = 0; t < 4; ++t) {
                        const float e = __builtin_amdgcn_exp2f(sacc[kb][j * 4 + t] - m_run);
                        lsum += e;
                        pk4[t] = f2bf(e);
                    }
                    *(u16x4*)(Pw + qc * 36 + j * 8 + 4 * hi) = pk4;
                }
#pragma unroll
                for (int s = 0; s < 2; ++s) {
                    const int c = kb * 2 + s;
                    const bf16x8 pf = *(const bf16x8*)(Pr + s * 16 + hi * 8);
#pragma unroll
                    for (int db = 0; db < 2; ++db) {
                        const int dr = db * 32 + qc;
                        const bf16x8 av = *(const bf16x8*)((const char*)Vsm + dr * 128 +
                                              ((c * 32 + hi * 16) ^ ((dr & 7) << 4)));
                        oacc[db] = __builtin_amdgcn_mfma_f32_32x32x16_bf16(av, pf,
                                                                           oacc[db], 0, 0, 0);
                    }
                }
            }
            lsum += __shfl_xor(lsum, 32);
            l_run += lsum;
        }
        __syncthreads();
    }

    const size_t row = (size_t)seg * 65536 + (size_t)bh * 2048 + qg;
    u16* op = opart + row * 64;
#pragma unroll
    for (int db = 0; db < 2; ++db)
#pragma unroll
        for (int j = 0; j < 4; ++j) {
            u16x4 o;
#pragma unroll
            for (int t = 0; t < 4; ++t) o[t] = f2bf(oacc[db][j * 4 + t]);
            *(u16x4*)(op + db * 32 + j * 8 + 4 * hi) = o;
        }
    if (hi == 0) { float2 t2; t2.x = m_run; t2.y = l_run; ml[row] = t2; }
}

__global__ __launch_bounds__(256) void attn_comb2(const u16* __restrict__ opart,
                                                  const float2* __restrict__ ml,
                                                  u16* __restrict__ Y) {
    const int idx = blockIdx.x * 256 + threadIdx.x;
    const int row = idx >> 4, d4 = idx & 15;
    const float2 ml0 = ml[row];
    const float2 ml1 = ml[65536 + row];
    const float m = fmaxf(ml0.x, ml1.x);
    const float w0 = __builtin_amdgcn_exp2f(ml0.x - m);
    const float w1 = __builtin_amdgcn_exp2f(ml1.x - m);
    const float inv = 1.0f / (ml0.y * w0 + ml1.y * w1);
    const float4 a = ldbf4(opart, (size_t)row * 16 + d4);
    const float4 b = ldbf4(opart, (size_t)(65536 + row) * 16 + d4);
    const int bh = row >> 11, q = row & 2047;
    const int b_ = bh >> 4, hh = bh & 15;
    u16x4 o;
    o[0] = f2bf((a.x * w0 + b.x * w1) * inv);
    o[1] = f2bf((a.y * w0 + b.y * w1) * inv);
    o[2] = f2bf((a.z * w0 + b.z * w1) * inv);
    o[3] = f2bf((a.w * w0 + b.w * w1) * inv);
    *(u16x4*)(Y + ((size_t)(b_ * 2048 + q)) * 1024 + hh * 64 + d4 * 4) = o;
}

// ---------------- host ----------------
extern "C" void kernel_launch(void* const* d_in, const int* in_sizes, int n_in,
                              void* d_out, int out_size, void* d_ws, size_t ws_size,
                              hipStream_t stream) {
    (void)in_sizes; (void)n_in; (void)out_size;
    const float* x      = (const float*)d_in[0];
    const float* w_qkv  = (const float*)d_in[2];
    const float* b_qkv  = (const float*)d_in[3];
    const float* w_proj = (const float*)d_in[4];
    const float* b_proj = (const float*)d_in[5];
    const float* w_fc1  = (const float*)d_in[6];
    const float* b_fc1  = (const float*)d_in[7];
    const float* w_fc2  = (const float*)d_in[8];
    const float* b_fc2  = (const float*)d_in[9];
    const float* g1     = (const float*)d_in[10];
    const float* be1    = (const float*)d_in[11];
    const float* g2     = (const float*)d_in[12];
    const float* be2    = (const float*)d_in[13];

    char* ws = (char*)d_ws;
    size_t off = 0;
    auto alloc = [&](size_t bytes) { size_t r = off; off += (bytes + 255) & ~(size_t)255; return r; };
    u16*   wt_qkv = (u16*)(ws + alloc((size_t)3072 * 1024 * 2));
    u16*   wt_prj = (u16*)(ws + alloc((size_t)1024 * 1024 * 2));
    u16*   wt_fc1 = (u16*)(ws + alloc((size_t)4096 * 1024 * 2));
    u16*   wt_fc2 = (u16*)(ws + alloc((size_t)1024 * 4096 * 2));
    u16*   hbuf   = (u16*)(ws + alloc((size_t)4096 * 1024 * 2));
    float* x1     = (float*)(ws + alloc((size_t)4096 * 1024 * 4));
    char*  big    = ws + alloc((size_t)33554432);
    u16* qb  = (u16*)(big);
    u16* kb  = (u16*)(big + 8388608);
    u16* vtb = (u16*)(big + 16777216);
    u16* yb  = (u16*)(big + 25165824);
    u16* act = (u16*)(big);
    if (off > ws_size) return;
    const size_t part_need = (size_t)4 * 4096 * 1024 * 2;
    if ((ws_size - off) < part_need) return;
    u16* part = (u16*)(ws + off);
    u16* opart = part;
    float2* mlp = (float2*)(ws + off + (size_t)2 * 65536 * 64 * 2);

    const dim3 blk(256);
    prep_kernel<<<dim3(16384), blk, 0, stream>>>(w_qkv, wt_qkv, w_proj, wt_prj,
                                                 w_fc1, wt_fc1, w_fc2, wt_fc2,
                                                 x, g1, be1, hbuf);
    // QKV: gemmv6, grid 768
    gemmv6<0, 1><<<dim3(768), blk, 0, stream>>>(hbuf, wt_qkv, b_qkv,
                                                qb, kb, vtb, 4096, 3072, 1024);
    // attention v7 + combine
    attn32_seg<<<dim3(1024), blk, 0, stream>>>(qb, kb, vtb, opart, mlp);
    attn_comb2<<<dim3(4096), blk, 0, stream>>>(opart, mlp, yb);
    // proj split-K=2 (gemmv6) + fused reduce+LN2
    gemmv6<5, 2><<<dim3(512), blk, 0, stream>>>(yb, wt_prj, nullptr,
                                                part, nullptr, nullptr, 4096, 1024, 1024);
    reduceLN_kernel<2><<<dim3(4096), blk, 0, stream>>>(part, b_proj, x, g2, be2,
                                                       x1, hbuf, 1048576);
    // FC1 + GELU: 8-phase 256^2, grid 256 x 512 threads
    gemm8<2, 1><<<dim3(256), dim3(512), 0, stream>>>(hbuf, wt_fc1, b_fc1,
                                                     act, 4096, 4096, 1024);
    // FC2 split-K=4: 8-phase 256^2, grid 256, then reduce(+bias+x1) -> d_out
    gemm8<5, 4><<<dim3(256), dim3(512), 0, stream>>>(act, wt_fc2, nullptr,
                                                     part, 4096, 1024, 4096);
    reduceN_kernel<4><<<dim3(4096), blk, 0, stream>>>(part, b_fc2, x1, (float*)d_out,
                                                      1048576, 256);
}

// Round 19
// 222.705 us; speedup vs baseline: 1.0099x; 1.0099x over previous
//
#include <hip/hip_runtime.h>
#include <hip/hip_bf16.h>
#include <stdint.h>

typedef unsigned short u16;
typedef __attribute__((ext_vector_type(8))) short bf16x8;
typedef __attribute__((ext_vector_type(4))) short bf16x4;
typedef __attribute__((ext_vector_type(4))) float f32x4;
typedef __attribute__((ext_vector_type(16))) float f32x16;
typedef __attribute__((ext_vector_type(4))) unsigned short u16x4;

#define DEVI static __device__ __forceinline__

DEVI u16 f2bf(float f) {
    unsigned int u = __builtin_bit_cast(unsigned int, f);
    return (u16)((u + 0x7fffu + ((u >> 16) & 1u)) >> 16);
}

DEVI float bf2f(u16 v) { return __builtin_bit_cast(float, ((unsigned)v) << 16); }

DEVI float4 ldbf4(const u16* p, size_t idx4) {
    const u16x4 v = ((const u16x4*)p)[idx4];
    float4 o;
    o.x = bf2f(v[0]); o.y = bf2f(v[1]); o.z = bf2f(v[2]); o.w = bf2f(v[3]);
    return o;
}

DEVI float gelu_f(float v) {
    // tanh-form GELU: x * sigmoid(1.5957691(x + 0.044715 x^3)); |err vs exact| <= ~3e-4
    const float z = 1.5957691216f * (v + 0.044715f * v * v * v);
    return v / (1.0f + __expf(-z));
}

DEVI void async_copy16(const void* g, void* l) {
    __builtin_amdgcn_global_load_lds((const __attribute__((address_space(1))) void*)g,
                                     (__attribute__((address_space(3))) void*)l,
                                     16, 0, 0);
}

// ============ prep kernel: 4x weight transpose-convert + LN1, one launch ============
__global__ __launch_bounds__(256) void prep_kernel(const float* __restrict__ wq, u16* __restrict__ dq,
                                                   const float* __restrict__ wp, u16* __restrict__ dp,
                                                   const float* __restrict__ w1, u16* __restrict__ d1,
                                                   const float* __restrict__ w2, u16* __restrict__ d2,
                                                   const float* __restrict__ x,
                                                   const float* __restrict__ g1,
                                                   const float* __restrict__ be1,
                                                   u16* __restrict__ ln1out) {
    __shared__ float tile[32][33];
    __shared__ float red[8];
    const int id = blockIdx.x;
    const int t = threadIdx.x;
    if (id >= 12288) {
        // ---- LN1 row ----
        const int row = id - 12288;
        const float4 v = ((const float4*)(x + (size_t)row * 1024))[t];
        float s  = v.x + v.y + v.z + v.w;
        float ss = v.x * v.x + v.y * v.y + v.z * v.z + v.w * v.w;
#pragma unroll
        for (int off = 32; off > 0; off >>= 1) {
            s  += __shfl_down(s, off);
            ss += __shfl_down(ss, off);
        }
        const int wv = t >> 6;
        if ((t & 63) == 0) { red[wv] = s; red[4 + wv] = ss; }
        __syncthreads();
        if (t == 0) {
            red[0] = red[0] + red[1] + red[2] + red[3];
            red[4] = red[4] + red[5] + red[6] + red[7];
        }
        __syncthreads();
        const float mean = red[0] * (1.0f / 1024.0f);
        const float var  = red[4] * (1.0f / 1024.0f) - mean * mean;
        const float rstd = rsqrtf(var + 1e-5f);
        const float4 gv = ((const float4*)g1)[t];
        const float4 bv = ((const float4*)be1)[t];
        u16x4 o;
        o[0] = f2bf((v.x - mean) * rstd * gv.x + bv.x);
        o[1] = f2bf((v.y - mean) * rstd * gv.y + bv.y);
        o[2] = f2bf((v.z - mean) * rstd * gv.z + bv.z);
        o[3] = f2bf((v.w - mean) * rstd * gv.w + bv.w);
        ((u16x4*)ln1out)[(size_t)row * 256 + t] = o;
        return;
    }
    // ---- transpose-convert tile ----
    const float* src; u16* dst; int K, N, k0, n0;
    if (id < 3072)      {               src = wq; dst = dq; K = 1024; N = 3072; k0 = (id & 31) << 5; n0 = (id >> 5) << 5; }
    else if (id < 4096) { int l = id - 3072; src = wp; dst = dp; K = 1024; N = 1024; k0 = (l & 31) << 5; n0 = (l >> 5) << 5; }
    else if (id < 8192) { int l = id - 4096; src = w1; dst = d1; K = 1024; N = 4096; k0 = (l & 31) << 5; n0 = (l >> 5) << 5; }
    else                { int l = id - 8192; src = w2; dst = d2; K = 4096; N = 1024; k0 = (l & 127) << 5; n0 = (l >> 7) << 5; }
    const int c = t & 31, r0 = t >> 5;
#pragma unroll
    for (int p = 0; p < 4; ++p) {
        const int r = r0 + p * 8;
        tile[r][c] = src[(size_t)(k0 + r) * N + n0 + c];
    }
    __syncthreads();
#pragma unroll
    for (int p = 0; p < 4; ++p) {
        const int r = r0 + p * 8;
        dst[(size_t)(n0 + r) * K + k0 + c] = f2bf(tile[c][r]);
    }
}

// ================= 128x128 GEMM, BK=64, single-buffer, m97-pure schedule =================
// Session conclusion: at K=1024, this occupancy-first structure (4 blocks/CU, 2 barriers/
// tile) beat every pipelined variant tried (8-phase x3, dbuf x2, 256-wide tiles x2).
DEVI void stage64(const char* g, size_t ldb, char* lds0, int lane, int wv) {
    const int colsw = ((lane & 3) << 4) ^ (lane & 32);  // inverse-swizzled source col bytes
    const int rl = lane >> 2;
#pragma unroll
    for (int i = 0; i < 4; ++i) {
        const int s = wv * 4 + i;            // slot 0..15
        const int kh = s >> 3, c = s & 7;    // k-half, 16-row subtile
        async_copy16(g + (size_t)(c * 16 + rl) * ldb + kh * 64 + colsw,
                     lds0 + s * 1024);
    }
}

// EPI 0: QKV scatter. EPI 2: gelu->bf16. EPI 5: bf16 partial (split-K).
template <int EPI, int SPLITK>
__global__ __launch_bounds__(256, 4) void gemmv6(const u16* __restrict__ A,
                                                 const u16* __restrict__ Bt,
                                                 const float* __restrict__ bias,
                                                 void* __restrict__ out0,
                                                 void* __restrict__ out1,
                                                 void* __restrict__ out2,
                                                 int M, int N, int K) {
    __shared__ __align__(16) char As[16384];
    __shared__ __align__(16) char Bs[16384];
    const int tid = threadIdx.x;
    const int lane = tid & 63, wv = tid >> 6;
    const int wr = wv >> 1, wc = wv & 1;        // 2M x 2N waves, 64x64 each
    const int g = lane >> 4, qq = lane & 15;
    const int rdoff = qq * 64 + ((g * 16) ^ ((qq & 8) << 2));  // swizzled read offset

    const int nwg = gridDim.x;
    int id = blockIdx.x;
    id = (id & 7) * (nwg >> 3) + (id >> 3);
    const int MT = M >> 7, NTn = N >> 7;
    const int slice = id / (MT * NTn);
    const int r2 = id % (MT * NTn);
    const int m0 = (r2 % MT) << 7;
    const int n0 = (r2 / MT) << 7;
    const int Ks = K / SPLITK;
    const int NT = Ks >> 6;
    const size_t ldb = (size_t)K * 2;

    const char* pa = (const char*)A + (size_t)m0 * ldb + (size_t)slice * Ks * 2;
    const char* pb = (const char*)Bt + (size_t)n0 * ldb + (size_t)slice * Ks * 2;

    f32x4 acc[4][4] = {};

    for (int t = 0; t < NT; ++t) {
        stage64(pa + (size_t)t * 128, ldb, As, lane, wv);
        stage64(pb + (size_t)t * 128, ldb, Bs, lane, wv);
        __syncthreads();
#pragma unroll
        for (int kh = 0; kh < 2; ++kh) {
            bf16x8 fa[4], fb[4];
#pragma unroll
            for (int fn = 0; fn < 4; ++fn)
                fb[fn] = *(const bf16x8*)(Bs + (kh * 8 + wc * 4 + fn) * 1024 + rdoff);
#pragma unroll
            for (int fm = 0; fm < 4; ++fm)
                fa[fm] = *(const bf16x8*)(As + (kh * 8 + wr * 4 + fm) * 1024 + rdoff);
#pragma unroll
            for (int fm = 0; fm < 4; ++fm)
#pragma unroll
                for (int fn = 0; fn < 4; ++fn)
                    acc[fm][fn] = __builtin_amdgcn_mfma_f32_16x16x32_bf16(fa[fm], fb[fn],
                                                                          acc[fm][fn], 0, 0, 0);
        }
        __syncthreads();
    }

#pragma unroll
    for (int fm = 0; fm < 4; ++fm) {
#pragma unroll
        for (int fn = 0; fn < 4; ++fn) {
            const int mrow = m0 + wr * 64 + fm * 16 + g * 4;
            const int ncol = n0 + wc * 64 + fn * 16 + qq;
            if constexpr (EPI == 0) {
                const float bs = bias[ncol];
                const int sec = ncol >> 10;
                const int hd_ = ncol & 1023;
                const int hh = hd_ >> 6, dd = hd_ & 63;
                if (sec == 2) {
                    const int b_ = mrow >> 11, l_ = mrow & 2047;
                    u16x4 pk;
#pragma unroll
                    for (int r = 0; r < 4; ++r) pk[r] = f2bf(acc[fm][fn][r] + bs);
                    *(u16x4*)((u16*)out2 + ((size_t)((b_ * 16 + hh) * 64 + dd)) * 2048 + l_) = pk;
                } else {
                    u16* dst = (sec == 0) ? (u16*)out0 : (u16*)out1;
                    // q-scale folds softmax 1/sqrt(hd) AND log2(e) for exp2-domain softmax
                    const float sc = (sec == 0) ? 0.1803368801f : 1.0f;
#pragma unroll
                    for (int r = 0; r < 4; ++r) {
                        const int mr = mrow + r;
                        const int b_ = mr >> 11, l_ = mr & 2047;
                        dst[((size_t)((b_ * 16 + hh) * 2048 + l_)) * 64 + dd] =
                            f2bf((acc[fm][fn][r] + bs) * sc);
                    }
                }
            } else if constexpr (EPI == 2) {
                const float bs = bias[ncol];
                u16* dst = (u16*)out0;
#pragma unroll
                for (int r = 0; r < 4; ++r)
                    dst[(size_t)(mrow + r) * N + ncol] = f2bf(gelu_f(acc[fm][fn][r] + bs));
            } else {  // EPI 5: bf16 partial for split-K
                u16* dst = (u16*)out0 + (size_t)slice * M * N;
#pragma unroll
                for (int r = 0; r < 4; ++r)
                    dst[(size_t)(mrow + r) * N + ncol] = f2bf(acc[fm][fn][r]);
            }
        }
    }
}

// split-K reduce (bf16 partials) + bias + residual -> f32 out (FC2 path)
template <int SPLIT>
__global__ __launch_bounds__(256) void reduceN_kernel(const u16* __restrict__ p,
                                                      const float* __restrict__ bias,
                                                      const float* __restrict__ res,
                                                      float* __restrict__ out,
                                                      int MN4, int N4) {
    const int i = blockIdx.x * 256 + threadIdx.x;   // one float4
    float4 s = ldbf4(p, i);
#pragma unroll
    for (int s2 = 1; s2 < SPLIT; ++s2) {
        const float4 q = ldbf4(p, (size_t)s2 * MN4 + i);
        s.x += q.x; s.y += q.y; s.z += q.z; s.w += q.w;
    }
    const float4 r = ((const float4*)res)[i];
    const float4 bs = ((const float4*)bias)[i & (N4 - 1)];
    float4 o;
    o.x = s.x + r.x + bs.x;
    o.y = s.y + r.y + bs.y;
    o.z = s.z + r.z + bs.z;
    o.w = s.w + r.w + bs.w;
    ((float4*)out)[i] = o;
}

// split-K reduce (bf16 partials) + bias + residual + LayerNorm fused (proj path)
template <int SPLIT>
__global__ __launch_bounds__(256) void reduceLN_kernel(const u16* __restrict__ p,
                                                       const float* __restrict__ bias,
                                                       const float* __restrict__ res,
                                                       const float* __restrict__ gw,
                                                       const float* __restrict__ bw,
                                                       float* __restrict__ xout,
                                                       u16* __restrict__ lnout,
                                                       int MN4) {
    const int row = blockIdx.x;
    const int t = threadIdx.x;
    const int i = row * 256 + t;
    float4 s = ldbf4(p, i);
#pragma unroll
    for (int s2 = 1; s2 < SPLIT; ++s2) {
        const float4 q = ldbf4(p, (size_t)s2 * MN4 + i);
        s.x += q.x; s.y += q.y; s.z += q.z; s.w += q.w;
    }
    const float4 r = ((const float4*)res)[i];
    const float4 bs = ((const float4*)bias)[t];
    float4 o;
    o.x = s.x + r.x + bs.x;
    o.y = s.y + r.y + bs.y;
    o.z = s.z + r.z + bs.z;
    o.w = s.w + r.w + bs.w;
    ((float4*)xout)[i] = o;
    float sum  = o.x + o.y + o.z + o.w;
    float ssum = o.x * o.x + o.y * o.y + o.z * o.z + o.w * o.w;
#pragma unroll
    for (int off = 32; off > 0; off >>= 1) {
        sum  += __shfl_down(sum, off);
        ssum += __shfl_down(ssum, off);
    }
    __shared__ float red[8];
    const int wv = t >> 6;
    if ((t & 63) == 0) { red[wv] = sum; red[4 + wv] = ssum; }
    __syncthreads();
    if (t == 0) {
        red[0] = red[0] + red[1] + red[2] + red[3];
        red[4] = red[4] + red[5] + red[6] + red[7];
    }
    __syncthreads();
    const float mean = red[0] * (1.0f / 1024.0f);
    const float var  = red[4] * (1.0f / 1024.0f) - mean * mean;
    const float rstd = rsqrtf(var + 1e-5f);
    const float4 gv = ((const float4*)gw)[t];
    const float4 bv = ((const float4*)bw)[t];
    u16x4 ov;
    ov[0] = f2bf((o.x - mean) * rstd * gv.x + bv.x);
    ov[1] = f2bf((o.y - mean) * rstd * gv.y + bv.y);
    ov[2] = f2bf((o.z - mean) * rstd * gv.z + bv.z);
    ov[3] = f2bf((o.w - mean) * rstd * gv.w + bv.w);
    ((u16x4*)lnout)[(size_t)row * 256 + t] = ov;
}

// ---------------- causal flash attention (unpaired, XCD-grouped, dbuf; R14/R15 plateau) ----
DEVI void stage_kv2(const char* kbase, const char* vbase, int key0,
                    u16* ksm, u16* vsm, int wv, int lane) {
#pragma unroll
    for (int i = 0; i < 2; ++i) {
        const int c = wv + i * 4;
        const int off = c * 1024 + lane * 16;
        const int row = off >> 7;
        const int scol = (off & 127) ^ ((row & 7) << 4);
        async_copy16(kbase + (size_t)key0 * 128 + (size_t)row * 128 + scol,
                     (char*)ksm + c * 1024);
    }
#pragma unroll
    for (int i = 0; i < 2; ++i) {
        const int c = wv + i * 4;
        const int row = c * 8 + (lane >> 3);
        const int scol = ((lane & 7) * 16) ^ ((row & 7) << 4);
        async_copy16(vbase + (size_t)row * 4096 + (size_t)key0 * 2 + scol,
                     (char*)vsm + c * 1024);
    }
}

__global__ __launch_bounds__(256, 3) void attn32_kernel(const u16* __restrict__ Q,
                                                        const u16* __restrict__ Kk,
                                                        const u16* __restrict__ Vt,
                                                        u16* __restrict__ Y) {
    const int id = blockIdx.x;
    const int bh = id & 31;                    // XCD = id % 8 = bh % 8 -> K/V L2-resident
    const int qb = 15 - (id >> 5);             // longest chains dispatch first
    const int b_ = bh >> 4, hh = bh & 15;
    const int tid = threadIdx.x;
    const int wv = tid >> 6, lane = tid & 63;
    const int hi = lane >> 5, qc = lane & 31;

    __shared__ __align__(16) u16 Ksm[2][4096];
    __shared__ __align__(16) u16 Vsm[2][4096];
    __shared__ __align__(16) u16 Pl[4][32 * 68];   // per-wave P[q][key], stride 68 u16

    const char* Kb = (const char*)(Kk + (size_t)bh * 2048 * 64);
    const char* Vb = (const char*)(Vt + (size_t)bh * 64 * 2048);
    u16* Pw = &Pl[wv][0];

    const int q0w = qb * 128 + wv * 32;
    const int qg = q0w + qc;
    const int ntile = qb * 2 + 2;
    const int ntile_w = qb * 2 + (wv >> 1) + 1;   // per-wave causal clamp

    bf16x8 qf[4];
    {
        const u16* Qp = Q + ((size_t)bh * 2048 + qg) * 64;
#pragma unroll
        for (int c = 0; c < 4; ++c)
            qf[c] = *(const bf16x8*)(Qp + c * 16 + hi * 8);
    }

    f32x16 oacc[2];
#pragma unroll
    for (int r = 0; r < 16; ++r) { oacc[0][r] = 0.0f; oacc[1][r] = 0.0f; }
    float m_run = -60000.0f, l_run = 0.0f;

    stage_kv2(Kb, Vb, 0, Ksm[0], Vsm[0], wv, lane);
    __syncthreads();
    int cur = 0;
    for (int kt = 0; kt < ntile; ++kt) {
        const int key0 = kt * 64;
        if (kt + 1 < ntile)
            stage_kv2(Kb, Vb, key0 + 64, Ksm[cur ^ 1], Vsm[cur ^ 1], wv, lane);
        if (kt < ntile_w) {
            // S^T = K * Q^T
            f32x16 sacc[2];
#pragma unroll
            for (int r = 0; r < 16; ++r) { sacc[0][r] = 0.0f; sacc[1][r] = 0.0f; }
#pragma unroll
            for (int c = 0; c < 4; ++c) {
#pragma unroll
                for (int kb = 0; kb < 2; ++kb) {
                    const int kr = kb * 32 + qc;
                    const bf16x8 ak = *(const bf16x8*)((const char*)Ksm[cur] + kr * 128 +
                                          ((c * 32 + hi * 16) ^ ((kr & 7) << 4)));
                    sacc[kb] = __builtin_amdgcn_mfma_f32_32x32x16_bf16(ak, qf[c],
                                                                       sacc[kb], 0, 0, 0);
                }
            }
            float pmax = -1e30f;
            if (key0 + 63 > q0w) {
#pragma unroll
                for (int kb = 0; kb < 2; ++kb)
#pragma unroll
                    for (int r = 0; r < 16; ++r) {
                        const int key = key0 + kb * 32 + (r & 3) + 8 * (r >> 2) + 4 * hi;
                        float s = sacc[kb][r];
                        if (key > qg) s = -1e30f;
                        sacc[kb][r] = s;
                        pmax = fmaxf(pmax, s);
                    }
            } else {
#pragma unroll
                for (int kb = 0; kb < 2; ++kb)
#pragma unroll
                    for (int r = 0; r < 16; ++r) pmax = fmaxf(pmax, sacc[kb][r]);
            }
            pmax = fmaxf(pmax, __shfl_xor(pmax, 32));
            if (pmax > m_run + 11.0f) {          // defer-max
                const float alpha = __builtin_amdgcn_exp2f(m_run - pmax);
#pragma unroll
                for (int r = 0; r < 16; ++r) { oacc[0][r] *= alpha; oacc[1][r] *= alpha; }
                l_run *= alpha;
                m_run = pmax;
            }
            float lsum = 0.0f;
#pragma unroll
            for (int kb = 0; kb < 2; ++kb)
#pragma unroll
                for (int j = 0; j < 4; ++j) {
                    u16x4 pk4;
#pragma unroll
                    for (int t = 0; t < 4; ++t) {
                        const float e = __builtin_amdgcn_exp2f(sacc[kb][j * 4 + t] - m_run);
                        lsum += e;
                        pk4[t] = f2bf(e);
                    }
                    *(u16x4*)(Pw + qc * 68 + kb * 32 + j * 8 + 4 * hi) = pk4;
                }
            lsum += __shfl_xor(lsum, 32);
            l_run += lsum;
            // O^T += V^T * P  (P read as two 8B bf16x4 loads: 2-way banks)
#pragma unroll
            for (int c = 0; c < 4; ++c) {
                const u16* pp = Pw + qc * 68 + c * 16 + hi * 8;
                union { bf16x8 v; struct { bf16x4 lo; bf16x4 hi2; } s; } u;
                u.s.lo  = *(const bf16x4*)(pp);
                u.s.hi2 = *(const bf16x4*)(pp + 4);
                const bf16x8 pf = u.v;
#pragma unroll
                for (int db = 0; db < 2; ++db) {
                    const int dr = db * 32 + qc;
                    const bf16x8 av = *(const bf16x8*)((const char*)Vsm[cur] + dr * 128 +
                                          ((c * 32 + hi * 16) ^ ((dr & 7) << 4)));
                    oacc[db] = __builtin_amdgcn_mfma_f32_32x32x16_bf16(av, pf,
                                                                       oacc[db], 0, 0, 0);
                }
            }
        }
        __syncthreads();
        cur ^= 1;
    }
    const float inv = 1.0f / l_run;
    u16* Yp = &Y[((size_t)(b_ * 2048 + qg)) * 1024 + hh * 64];
#pragma unroll
    for (int db = 0; db < 2; ++db)
#pragma unroll
        for (int j = 0; j < 4; ++j) {
            u16x4 o;
#pragma unroll
            for (int t = 0; t < 4; ++t) o[t] = f2bf(oacc[db][j * 4 + t] * inv);
            *(u16x4*)(Yp + db * 32 + j * 8 + 4 * hi) = o;
        }
}

// ---------------- host ----------------
extern "C" void kernel_launch(void* const* d_in, const int* in_sizes, int n_in,
                              void* d_out, int out_size, void* d_ws, size_t ws_size,
                              hipStream_t stream) {
    (void)in_sizes; (void)n_in; (void)out_size;
    const float* x      = (const float*)d_in[0];
    const float* w_qkv  = (const float*)d_in[2];
    const float* b_qkv  = (const float*)d_in[3];
    const float* w_proj = (const float*)d_in[4];
    const float* b_proj = (const float*)d_in[5];
    const float* w_fc1  = (const float*)d_in[6];
    const float* b_fc1  = (const float*)d_in[7];
    const float* w_fc2  = (const float*)d_in[8];
    const float* b_fc2  = (const float*)d_in[9];
    const float* g1     = (const float*)d_in[10];
    const float* be1    = (const float*)d_in[11];
    const float* g2     = (const float*)d_in[12];
    const float* be2    = (const float*)d_in[13];

    char* ws = (char*)d_ws;
    size_t off = 0;
    auto alloc = [&](size_t bytes) { size_t r = off; off += (bytes + 255) & ~(size_t)255; return r; };
    u16*   wt_qkv = (u16*)(ws + alloc((size_t)3072 * 1024 * 2));
    u16*   wt_prj = (u16*)(ws + alloc((size_t)1024 * 1024 * 2));
    u16*   wt_fc1 = (u16*)(ws + alloc((size_t)4096 * 1024 * 2));
    u16*   wt_fc2 = (u16*)(ws + alloc((size_t)1024 * 4096 * 2));
    u16*   hbuf   = (u16*)(ws + alloc((size_t)4096 * 1024 * 2));
    float* x1     = (float*)(ws + alloc((size_t)4096 * 1024 * 4));
    char*  big    = ws + alloc((size_t)33554432);
    u16* qb  = (u16*)(big);
    u16* kb  = (u16*)(big + 8388608);
    u16* vtb = (u16*)(big + 16777216);
    u16* yb  = (u16*)(big + 25165824);
    u16* act = (u16*)(big);
    if (off > ws_size) return;
    // bf16 split-K partials: 4 x 8MB = 32MB (proj sK4 and FC2 sK4 both fit exactly)
    const size_t part_need = (size_t)4 * 4096 * 1024 * 2;
    if ((ws_size - off) < part_need) return;
    u16* part = (u16*)(ws + off);

    const dim3 blk(256);
    // prep: 4x tcvt + LN1 in one launch (16384 blocks)
    prep_kernel<<<dim3(16384), blk, 0, stream>>>(w_qkv, wt_qkv, w_proj, wt_prj,
                                                 w_fc1, wt_fc1, w_fc2, wt_fc2,
                                                 x, g1, be1, hbuf);
    // QKV: grid 32*24 = 768
    gemmv6<0, 1><<<dim3(768), blk, 0, stream>>>(hbuf, wt_qkv, b_qkv,
                                                qb, kb, vtb, 4096, 3072, 1024);
    // attention: unpaired 16 chunks x 32 bh = 512 blocks, XCD-grouped, longest first
    attn32_kernel<<<dim3(512), blk, 0, stream>>>(qb, kb, vtb, yb);
    // proj split-K=4 (bf16 partials): grid 1024 (4 blocks/CU), then fused reduce+LN2
    gemmv6<5, 4><<<dim3(1024), blk, 0, stream>>>(yb, wt_prj, nullptr,
                                                 part, nullptr, nullptr, 4096, 1024, 1024);
    reduceLN_kernel<4><<<dim3(4096), blk, 0, stream>>>(part, b_proj, x, g2, be2,
                                                       x1, hbuf, 1048576);
    // FC1 + GELU: grid 1024
    gemmv6<2, 1><<<dim3(1024), blk, 0, stream>>>(hbuf, wt_fc1, b_fc1,
                                                 act, nullptr, nullptr, 4096, 4096, 1024);
    // FC2 split-K=4 (bf16 partials): grid 1024, then reduce(+bias+x1) -> d_out
    gemmv6<5, 4><<<dim3(1024), blk, 0, stream>>>(act, wt_fc2, nullptr,
                                                 part, nullptr, nullptr, 4096, 1024, 4096);
    reduceN_kernel<4><<<dim3(4096), blk, 0, stream>>>(part, b_fc2, x1, (float*)d_out,
                                                      1048576, 256);
}

// Round 20
// 220.758 us; speedup vs baseline: 1.0188x; 1.0088x over previous
//
#include <hip/hip_runtime.h>
#include <hip/hip_bf16.h>
#include <stdint.h>

typedef unsigned short u16;
typedef __attribute__((ext_vector_type(8))) short bf16x8;
typedef __attribute__((ext_vector_type(4))) short bf16x4;
typedef __attribute__((ext_vector_type(4))) float f32x4;
typedef __attribute__((ext_vector_type(16))) float f32x16;
typedef __attribute__((ext_vector_type(4))) unsigned short u16x4;

#define DEVI static __device__ __forceinline__

DEVI u16 f2bf(float f) {
    unsigned int u = __builtin_bit_cast(unsigned int, f);
    return (u16)((u + 0x7fffu + ((u >> 16) & 1u)) >> 16);
}

DEVI float bf2f(u16 v) { return __builtin_bit_cast(float, ((unsigned)v) << 16); }

DEVI float4 ldbf4(const u16* p, size_t idx4) {
    const u16x4 v = ((const u16x4*)p)[idx4];
    float4 o;
    o.x = bf2f(v[0]); o.y = bf2f(v[1]); o.z = bf2f(v[2]); o.w = bf2f(v[3]);
    return o;
}

DEVI float gelu_f(float v) {
    // tanh-form GELU: x * sigmoid(1.5957691(x + 0.044715 x^3)); |err vs exact| <= ~3e-4
    const float z = 1.5957691216f * (v + 0.044715f * v * v * v);
    return v / (1.0f + __expf(-z));
}

DEVI void async_copy16(const void* g, void* l) {
    __builtin_amdgcn_global_load_lds((const __attribute__((address_space(1))) void*)g,
                                     (__attribute__((address_space(3))) void*)l,
                                     16, 0, 0);
}

// ============ prep kernel: 4x weight transpose-convert + LN1, one launch ============
__global__ __launch_bounds__(256) void prep_kernel(const float* __restrict__ wq, u16* __restrict__ dq,
                                                   const float* __restrict__ wp, u16* __restrict__ dp,
                                                   const float* __restrict__ w1, u16* __restrict__ d1,
                                                   const float* __restrict__ w2, u16* __restrict__ d2,
                                                   const float* __restrict__ x,
                                                   const float* __restrict__ g1,
                                                   const float* __restrict__ be1,
                                                   u16* __restrict__ ln1out) {
    __shared__ float tile[32][33];
    __shared__ float red[8];
    const int id = blockIdx.x;
    const int t = threadIdx.x;
    if (id >= 12288) {
        // ---- LN1 row ----
        const int row = id - 12288;
        const float4 v = ((const float4*)(x + (size_t)row * 1024))[t];
        float s  = v.x + v.y + v.z + v.w;
        float ss = v.x * v.x + v.y * v.y + v.z * v.z + v.w * v.w;
#pragma unroll
        for (int off = 32; off > 0; off >>= 1) {
            s  += __shfl_down(s, off);
            ss += __shfl_down(ss, off);
        }
        const int wv = t >> 6;
        if ((t & 63) == 0) { red[wv] = s; red[4 + wv] = ss; }
        __syncthreads();
        if (t == 0) {
            red[0] = red[0] + red[1] + red[2] + red[3];
            red[4] = red[4] + red[5] + red[6] + red[7];
        }
        __syncthreads();
        const float mean = red[0] * (1.0f / 1024.0f);
        const float var  = red[4] * (1.0f / 1024.0f) - mean * mean;
        const float rstd = rsqrtf(var + 1e-5f);
        const float4 gv = ((const float4*)g1)[t];
        const float4 bv = ((const float4*)be1)[t];
        u16x4 o;
        o[0] = f2bf((v.x - mean) * rstd * gv.x + bv.x);
        o[1] = f2bf((v.y - mean) * rstd * gv.y + bv.y);
        o[2] = f2bf((v.z - mean) * rstd * gv.z + bv.z);
        o[3] = f2bf((v.w - mean) * rstd * gv.w + bv.w);
        ((u16x4*)ln1out)[(size_t)row * 256 + t] = o;
        return;
    }
    // ---- transpose-convert tile ----
    const float* src; u16* dst; int K, N, k0, n0;
    if (id < 3072)      {               src = wq; dst = dq; K = 1024; N = 3072; k0 = (id & 31) << 5; n0 = (id >> 5) << 5; }
    else if (id < 4096) { int l = id - 3072; src = wp; dst = dp; K = 1024; N = 1024; k0 = (l & 31) << 5; n0 = (l >> 5) << 5; }
    else if (id < 8192) { int l = id - 4096; src = w1; dst = d1; K = 1024; N = 4096; k0 = (l & 31) << 5; n0 = (l >> 5) << 5; }
    else                { int l = id - 8192; src = w2; dst = d2; K = 4096; N = 1024; k0 = (l & 127) << 5; n0 = (l >> 7) << 5; }
    const int c = t & 31, r0 = t >> 5;
#pragma unroll
    for (int p = 0; p < 4; ++p) {
        const int r = r0 + p * 8;
        tile[r][c] = src[(size_t)(k0 + r) * N + n0 + c];
    }
    __syncthreads();
#pragma unroll
    for (int p = 0; p < 4; ++p) {
        const int r = r0 + p * 8;
        dst[(size_t)(n0 + r) * K + k0 + c] = f2bf(tile[c][r]);
    }
}

// ================= 128x128 GEMM, BK=64, single-buffer, m97-pure schedule =================
// Session conclusion: at K=1024, this occupancy-first structure (4 blocks/CU, 2 barriers/
// tile) beat every pipelined variant tried (8-phase x3, dbuf x2, 256-wide tiles x2).
DEVI void stage64(const char* g, size_t ldb, char* lds0, int lane, int wv) {
    const int colsw = ((lane & 3) << 4) ^ (lane & 32);  // inverse-swizzled source col bytes
    const int rl = lane >> 2;
#pragma unroll
    for (int i = 0; i < 4; ++i) {
        const int s = wv * 4 + i;            // slot 0..15
        const int kh = s >> 3, c = s & 7;    // k-half, 16-row subtile
        async_copy16(g + (size_t)(c * 16 + rl) * ldb + kh * 64 + colsw,
                     lds0 + s * 1024);
    }
}

// EPI 0: QKV scatter. EPI 2: gelu->bf16. EPI 5: bf16 partial (split-K).
template <int EPI, int SPLITK>
__global__ __launch_bounds__(256, 4) void gemmv6(const u16* __restrict__ A,
                                                 const u16* __restrict__ Bt,
                                                 const float* __restrict__ bias,
                                                 void* __restrict__ out0,
                                                 void* __restrict__ out1,
                                                 void* __restrict__ out2,
                                                 int M, int N, int K) {
    __shared__ __align__(16) char As[16384];
    __shared__ __align__(16) char Bs[16384];
    const int tid = threadIdx.x;
    const int lane = tid & 63, wv = tid >> 6;
    const int wr = wv >> 1, wc = wv & 1;        // 2M x 2N waves, 64x64 each
    const int g = lane >> 4, qq = lane & 15;
    const int rdoff = qq * 64 + ((g * 16) ^ ((qq & 8) << 2));  // swizzled read offset

    const int nwg = gridDim.x;
    int id = blockIdx.x;
    id = (id & 7) * (nwg >> 3) + (id >> 3);
    const int MT = M >> 7, NTn = N >> 7;
    const int slice = id / (MT * NTn);
    const int r2 = id % (MT * NTn);
    const int m0 = (r2 % MT) << 7;
    const int n0 = (r2 / MT) << 7;
    const int Ks = K / SPLITK;
    const int NT = Ks >> 6;
    const size_t ldb = (size_t)K * 2;

    const char* pa = (const char*)A + (size_t)m0 * ldb + (size_t)slice * Ks * 2;
    const char* pb = (const char*)Bt + (size_t)n0 * ldb + (size_t)slice * Ks * 2;

    f32x4 acc[4][4] = {};

    for (int t = 0; t < NT; ++t) {
        stage64(pa + (size_t)t * 128, ldb, As, lane, wv);
        stage64(pb + (size_t)t * 128, ldb, Bs, lane, wv);
        __syncthreads();
#pragma unroll
        for (int kh = 0; kh < 2; ++kh) {
            bf16x8 fa[4], fb[4];
#pragma unroll
            for (int fn = 0; fn < 4; ++fn)
                fb[fn] = *(const bf16x8*)(Bs + (kh * 8 + wc * 4 + fn) * 1024 + rdoff);
#pragma unroll
            for (int fm = 0; fm < 4; ++fm)
                fa[fm] = *(const bf16x8*)(As + (kh * 8 + wr * 4 + fm) * 1024 + rdoff);
#pragma unroll
            for (int fm = 0; fm < 4; ++fm)
#pragma unroll
                for (int fn = 0; fn < 4; ++fn)
                    acc[fm][fn] = __builtin_amdgcn_mfma_f32_16x16x32_bf16(fa[fm], fb[fn],
                                                                          acc[fm][fn], 0, 0, 0);
        }
        __syncthreads();
    }

#pragma unroll
    for (int fm = 0; fm < 4; ++fm) {
#pragma unroll
        for (int fn = 0; fn < 4; ++fn) {
            const int mrow = m0 + wr * 64 + fm * 16 + g * 4;
            const int ncol = n0 + wc * 64 + fn * 16 + qq;
            if constexpr (EPI == 0) {
                const float bs = bias[ncol];
                const int sec = ncol >> 10;
                const int hd_ = ncol & 1023;
                const int hh = hd_ >> 6, dd = hd_ & 63;
                if (sec == 2) {
                    const int b_ = mrow >> 11, l_ = mrow & 2047;
                    u16x4 pk;
#pragma unroll
                    for (int r = 0; r < 4; ++r) pk[r] = f2bf(acc[fm][fn][r] + bs);
                    *(u16x4*)((u16*)out2 + ((size_t)((b_ * 16 + hh) * 64 + dd)) * 2048 + l_) = pk;
                } else {
                    u16* dst = (sec == 0) ? (u16*)out0 : (u16*)out1;
                    // q-scale folds softmax 1/sqrt(hd) AND log2(e) for exp2-domain softmax
                    const float sc = (sec == 0) ? 0.1803368801f : 1.0f;
#pragma unroll
                    for (int r = 0; r < 4; ++r) {
                        const int mr = mrow + r;
                        const int b_ = mr >> 11, l_ = mr & 2047;
                        dst[((size_t)((b_ * 16 + hh) * 2048 + l_)) * 64 + dd] =
                            f2bf((acc[fm][fn][r] + bs) * sc);
                    }
                }
            } else if constexpr (EPI == 2) {
                const float bs = bias[ncol];
                u16* dst = (u16*)out0;
#pragma unroll
                for (int r = 0; r < 4; ++r)
                    dst[(size_t)(mrow + r) * N + ncol] = f2bf(gelu_f(acc[fm][fn][r] + bs));
            } else {  // EPI 5: bf16 partial for split-K
                u16* dst = (u16*)out0 + (size_t)slice * M * N;
#pragma unroll
                for (int r = 0; r < 4; ++r)
                    dst[(size_t)(mrow + r) * N + ncol] = f2bf(acc[fm][fn][r]);
            }
        }
    }
}

// split-K reduce (bf16 partials) + bias + residual -> f32 out (FC2 path)
template <int SPLIT>
__global__ __launch_bounds__(256) void reduceN_kernel(const u16* __restrict__ p,
                                                      const float* __restrict__ bias,
                                                      const float* __restrict__ res,
                                                      float* __restrict__ out,
                                                      int MN4, int N4) {
    const int i = blockIdx.x * 256 + threadIdx.x;   // one float4
    float4 s = ldbf4(p, i);
#pragma unroll
    for (int s2 = 1; s2 < SPLIT; ++s2) {
        const float4 q = ldbf4(p, (size_t)s2 * MN4 + i);
        s.x += q.x; s.y += q.y; s.z += q.z; s.w += q.w;
    }
    const float4 r = ((const float4*)res)[i];
    const float4 bs = ((const float4*)bias)[i & (N4 - 1)];
    float4 o;
    o.x = s.x + r.x + bs.x;
    o.y = s.y + r.y + bs.y;
    o.z = s.z + r.z + bs.z;
    o.w = s.w + r.w + bs.w;
    ((float4*)out)[i] = o;
}

// split-K reduce (bf16 partials) + bias + residual + LayerNorm fused (proj path)
template <int SPLIT>
__global__ __launch_bounds__(256) void reduceLN_kernel(const u16* __restrict__ p,
                                                       const float* __restrict__ bias,
                                                       const float* __restrict__ res,
                                                       const float* __restrict__ gw,
                                                       const float* __restrict__ bw,
                                                       float* __restrict__ xout,
                                                       u16* __restrict__ lnout,
                                                       int MN4) {
    const int row = blockIdx.x;
    const int t = threadIdx.x;
    const int i = row * 256 + t;
    float4 s = ldbf4(p, i);
#pragma unroll
    for (int s2 = 1; s2 < SPLIT; ++s2) {
        const float4 q = ldbf4(p, (size_t)s2 * MN4 + i);
        s.x += q.x; s.y += q.y; s.z += q.z; s.w += q.w;
    }
    const float4 r = ((const float4*)res)[i];
    const float4 bs = ((const float4*)bias)[t];
    float4 o;
    o.x = s.x + r.x + bs.x;
    o.y = s.y + r.y + bs.y;
    o.z = s.z + r.z + bs.z;
    o.w = s.w + r.w + bs.w;
    ((float4*)xout)[i] = o;
    float sum  = o.x + o.y + o.z + o.w;
    float ssum = o.x * o.x + o.y * o.y + o.z * o.z + o.w * o.w;
#pragma unroll
    for (int off = 32; off > 0; off >>= 1) {
        sum  += __shfl_down(sum, off);
        ssum += __shfl_down(ssum, off);
    }
    __shared__ float red[8];
    const int wv = t >> 6;
    if ((t & 63) == 0) { red[wv] = sum; red[4 + wv] = ssum; }
    __syncthreads();
    if (t == 0) {
        red[0] = red[0] + red[1] + red[2] + red[3];
        red[4] = red[4] + red[5] + red[6] + red[7];
    }
    __syncthreads();
    const float mean = red[0] * (1.0f / 1024.0f);
    const float var  = red[4] * (1.0f / 1024.0f) - mean * mean;
    const float rstd = rsqrtf(var + 1e-5f);
    const float4 gv = ((const float4*)gw)[t];
    const float4 bv = ((const float4*)bw)[t];
    u16x4 ov;
    ov[0] = f2bf((o.x - mean) * rstd * gv.x + bv.x);
    ov[1] = f2bf((o.y - mean) * rstd * gv.y + bv.y);
    ov[2] = f2bf((o.z - mean) * rstd * gv.z + bv.z);
    ov[3] = f2bf((o.w - mean) * rstd * gv.w + bv.w);
    ((u16x4*)lnout)[(size_t)row * 256 + t] = ov;
}

// ---------------- causal flash attention (unpaired, XCD-grouped, dbuf; session plateau) ----
DEVI void stage_kv2(const char* kbase, const char* vbase, int key0,
                    u16* ksm, u16* vsm, int wv, int lane) {
#pragma unroll
    for (int i = 0; i < 2; ++i) {
        const int c = wv + i * 4;
        const int off = c * 1024 + lane * 16;
        const int row = off >> 7;
        const int scol = (off & 127) ^ ((row & 7) << 4);
        async_copy16(kbase + (size_t)key0 * 128 + (size_t)row * 128 + scol,
                     (char*)ksm + c * 1024);
    }
#pragma unroll
    for (int i = 0; i < 2; ++i) {
        const int c = wv + i * 4;
        const int row = c * 8 + (lane >> 3);
        const int scol = ((lane & 7) * 16) ^ ((row & 7) << 4);
        async_copy16(vbase + (size_t)row * 4096 + (size_t)key0 * 2 + scol,
                     (char*)vsm + c * 1024);
    }
}

__global__ __launch_bounds__(256, 3) void attn32_kernel(const u16* __restrict__ Q,
                                                        const u16* __restrict__ Kk,
                                                        const u16* __restrict__ Vt,
                                                        u16* __restrict__ Y) {
    const int id = blockIdx.x;
    const int bh = id & 31;                    // XCD = id % 8 = bh % 8 -> K/V L2-resident
    const int qb = 15 - (id >> 5);             // longest chains dispatch first
    const int b_ = bh >> 4, hh = bh & 15;
    const int tid = threadIdx.x;
    const int wv = tid >> 6, lane = tid & 63;
    const int hi = lane >> 5, qc = lane & 31;

    __shared__ __align__(16) u16 Ksm[2][4096];
    __shared__ __align__(16) u16 Vsm[2][4096];
    __shared__ __align__(16) u16 Pl[4][32 * 68];   // per-wave P[q][key], stride 68 u16

    const char* Kb = (const char*)(Kk + (size_t)bh * 2048 * 64);
    const char* Vb = (const char*)(Vt + (size_t)bh * 64 * 2048);
    u16* Pw = &Pl[wv][0];

    const int q0w = qb * 128 + wv * 32;
    const int qg = q0w + qc;
    const int ntile = qb * 2 + 2;
    const int ntile_w = qb * 2 + (wv >> 1) + 1;   // per-wave causal clamp

    bf16x8 qf[4];
    {
        const u16* Qp = Q + ((size_t)bh * 2048 + qg) * 64;
#pragma unroll
        for (int c = 0; c < 4; ++c)
            qf[c] = *(const bf16x8*)(Qp + c * 16 + hi * 8);
    }

    f32x16 oacc[2];
#pragma unroll
    for (int r = 0; r < 16; ++r) { oacc[0][r] = 0.0f; oacc[1][r] = 0.0f; }
    float m_run = -60000.0f, l_run = 0.0f;

    stage_kv2(Kb, Vb, 0, Ksm[0], Vsm[0], wv, lane);
    __syncthreads();
    int cur = 0;
    for (int kt = 0; kt < ntile; ++kt) {
        const int key0 = kt * 64;
        if (kt + 1 < ntile)
            stage_kv2(Kb, Vb, key0 + 64, Ksm[cur ^ 1], Vsm[cur ^ 1], wv, lane);
        if (kt < ntile_w) {
            // S^T = K * Q^T
            f32x16 sacc[2];
#pragma unroll
            for (int r = 0; r < 16; ++r) { sacc[0][r] = 0.0f; sacc[1][r] = 0.0f; }
#pragma unroll
            for (int c = 0; c < 4; ++c) {
#pragma unroll
                for (int kb = 0; kb < 2; ++kb) {
                    const int kr = kb * 32 + qc;
                    const bf16x8 ak = *(const bf16x8*)((const char*)Ksm[cur] + kr * 128 +
                                          ((c * 32 + hi * 16) ^ ((kr & 7) << 4)));
                    sacc[kb] = __builtin_amdgcn_mfma_f32_32x32x16_bf16(ak, qf[c],
                                                                       sacc[kb], 0, 0, 0);
                }
            }
            float pmax = -1e30f;
            if (key0 + 63 > q0w) {
#pragma unroll
                for (int kb = 0; kb < 2; ++kb)
#pragma unroll
                    for (int r = 0; r < 16; ++r) {
                        const int key = key0 + kb * 32 + (r & 3) + 8 * (r >> 2) + 4 * hi;
                        float s = sacc[kb][r];
                        if (key > qg) s = -1e30f;
                        sacc[kb][r] = s;
                        pmax = fmaxf(pmax, s);
                    }
            } else {
#pragma unroll
                for (int kb = 0; kb < 2; ++kb)
#pragma unroll
                    for (int r = 0; r < 16; ++r) pmax = fmaxf(pmax, sacc[kb][r]);
            }
            pmax = fmaxf(pmax, __shfl_xor(pmax, 32));
            if (pmax > m_run + 11.0f) {          // defer-max
                const float alpha = __builtin_amdgcn_exp2f(m_run - pmax);
#pragma unroll
                for (int r = 0; r < 16; ++r) { oacc[0][r] *= alpha; oacc[1][r] *= alpha; }
                l_run *= alpha;
                m_run = pmax;
            }
            float lsum = 0.0f;
#pragma unroll
            for (int kb = 0; kb < 2; ++kb)
#pragma unroll
                for (int j = 0; j < 4; ++j) {
                    u16x4 pk4;
#pragma unroll
                    for (int t = 0; t < 4; ++t) {
                        const float e = __builtin_amdgcn_exp2f(sacc[kb][j * 4 + t] - m_run);
                        lsum += e;
                        pk4[t] = f2bf(e);
                    }
                    *(u16x4*)(Pw + qc * 68 + kb * 32 + j * 8 + 4 * hi) = pk4;
                }
            lsum += __shfl_xor(lsum, 32);
            l_run += lsum;
            // O^T += V^T * P  (P read as two 8B bf16x4 loads: 2-way banks)
#pragma unroll
            for (int c = 0; c < 4; ++c) {
                const u16* pp = Pw + qc * 68 + c * 16 + hi * 8;
                union { bf16x8 v; struct { bf16x4 lo; bf16x4 hi2; } s; } u;
                u.s.lo  = *(const bf16x4*)(pp);
                u.s.hi2 = *(const bf16x4*)(pp + 4);
                const bf16x8 pf = u.v;
#pragma unroll
                for (int db = 0; db < 2; ++db) {
                    const int dr = db * 32 + qc;
                    const bf16x8 av = *(const bf16x8*)((const char*)Vsm[cur] + dr * 128 +
                                          ((c * 32 + hi * 16) ^ ((dr & 7) << 4)));
                    oacc[db] = __builtin_amdgcn_mfma_f32_32x32x16_bf16(av, pf,
                                                                       oacc[db], 0, 0, 0);
                }
            }
        }
        __syncthreads();
        cur ^= 1;
    }
    const float inv = 1.0f / l_run;
    u16* Yp = &Y[((size_t)(b_ * 2048 + qg)) * 1024 + hh * 64];
#pragma unroll
    for (int db = 0; db < 2; ++db)
#pragma unroll
        for (int j = 0; j < 4; ++j) {
            u16x4 o;
#pragma unroll
            for (int t = 0; t < 4; ++t) o[t] = f2bf(oacc[db][j * 4 + t] * inv);
            *(u16x4*)(Yp + db * 32 + j * 8 + 4 * hi) = o;
        }
}

// ---------------- host ----------------
extern "C" void kernel_launch(void* const* d_in, const int* in_sizes, int n_in,
                              void* d_out, int out_size, void* d_ws, size_t ws_size,
                              hipStream_t stream) {
    (void)in_sizes; (void)n_in; (void)out_size;
    const float* x      = (const float*)d_in[0];
    const float* w_qkv  = (const float*)d_in[2];
    const float* b_qkv  = (const float*)d_in[3];
    const float* w_proj = (const float*)d_in[4];
    const float* b_proj = (const float*)d_in[5];
    const float* w_fc1  = (const float*)d_in[6];
    const float* b_fc1  = (const float*)d_in[7];
    const float* w_fc2  = (const float*)d_in[8];
    const float* b_fc2  = (const float*)d_in[9];
    const float* g1     = (const float*)d_in[10];
    const float* be1    = (const float*)d_in[11];
    const float* g2     = (const float*)d_in[12];
    const float* be2    = (const float*)d_in[13];

    char* ws = (char*)d_ws;
    size_t off = 0;
    auto alloc = [&](size_t bytes) { size_t r = off; off += (bytes + 255) & ~(size_t)255; return r; };
    u16*   wt_qkv = (u16*)(ws + alloc((size_t)3072 * 1024 * 2));
    u16*   wt_prj = (u16*)(ws + alloc((size_t)1024 * 1024 * 2));
    u16*   wt_fc1 = (u16*)(ws + alloc((size_t)4096 * 1024 * 2));
    u16*   wt_fc2 = (u16*)(ws + alloc((size_t)1024 * 4096 * 2));
    u16*   hbuf   = (u16*)(ws + alloc((size_t)4096 * 1024 * 2));
    float* x1     = (float*)(ws + alloc((size_t)4096 * 1024 * 4));
    char*  big    = ws + alloc((size_t)33554432);
    u16* qb  = (u16*)(big);
    u16* kb  = (u16*)(big + 8388608);
    u16* vtb = (u16*)(big + 16777216);
    u16* yb  = (u16*)(big + 25165824);
    u16* act = (u16*)(big);
    if (off > ws_size) return;
    // bf16 split-K partials: FC2 sK4 = 4 x 8MB = 32MB (proj sK2 = 16MB reuses same region)
    const size_t part_need = (size_t)4 * 4096 * 1024 * 2;
    if ((ws_size - off) < part_need) return;
    u16* part = (u16*)(ws + off);

    const dim3 blk(256);
    // prep: 4x tcvt + LN1 in one launch (16384 blocks)
    prep_kernel<<<dim3(16384), blk, 0, stream>>>(w_qkv, wt_qkv, w_proj, wt_prj,
                                                 w_fc1, wt_fc1, w_fc2, wt_fc2,
                                                 x, g1, be1, hbuf);
    // QKV: grid 32*24 = 768
    gemmv6<0, 1><<<dim3(768), blk, 0, stream>>>(hbuf, wt_qkv, b_qkv,
                                                qb, kb, vtb, 4096, 3072, 1024);
    // attention: unpaired 16 chunks x 32 bh = 512 blocks, XCD-grouped, longest first
    attn32_kernel<<<dim3(512), blk, 0, stream>>>(qb, kb, vtb, yb);
    // proj split-K=2 (bf16 partials): grid 512, then fused reduce+LN2 -> x1, hbuf
    gemmv6<5, 2><<<dim3(512), blk, 0, stream>>>(yb, wt_prj, nullptr,
                                                part, nullptr, nullptr, 4096, 1024, 1024);
    reduceLN_kernel<2><<<dim3(4096), blk, 0, stream>>>(part, b_proj, x, g2, be2,
                                                       x1, hbuf, 1048576);
    // FC1 + GELU: grid 1024
    gemmv6<2, 1><<<dim3(1024), blk, 0, stream>>>(hbuf, wt_fc1, b_fc1,
                                                 act, nullptr, nullptr, 4096, 4096, 1024);
    // FC2 split-K=4 (bf16 partials): grid 1024, then reduce(+bias+x1) -> d_out
    gemmv6<5, 4><<<dim3(1024), blk, 0, stream>>>(act, wt_fc2, nullptr,
                                                 part, nullptr, nullptr, 4096, 1024, 4096);
    reduceN_kernel<4><<<dim3(4096), blk, 0, stream>>>(part, b_fc2, x1, (float*)d_out,
                                                      1048576, 256);
}